// Round 6
// baseline (321.171 us; speedup 1.0000x reference)
//
#include <hip/hip_runtime.h>
#include <hip/hip_bf16.h>
#include <hip/hip_fp16.h>

// ---------------------------------------------------------------------------
// FakeQuantLinear (Q4_K_M fake-quant + GEMM): out = x @ fq(W)^T + bias
// R12: R10 + bank-conflict fix. R10's [k16][row][2x16B] layout put each
//      quarter-wave's 16 lanes on only 4 bank-quads (word = row*8 mod 32,
//      4-way, SQ_LDS_BANK_CONFLICT 1.26e7, -26%). Fix: store (row,khalf) at
//      slot khalf ^ ((row>>2)&1). Read word = row*8 + slot*4 mod 32 then
//      covers all 8 bank-quads 2-way per quarter-wave (2-way = free, m136).
//      Staging keeps the mandatory linear LDS dest (base + tid*16); the
//      permutation is applied to the GLOBAL source instead (G21):
//      skoff = ((tid&1) ^ ((tid>>3)&1))*8  (staged row = tid>>1).
//      Everything else identical to R10 (correctness proven: absmax matched
//      R6 bit-for-bit): 256x128 tile, BK=64 single-buffer, 2 blocks/CU,
//      mfma_f32_32x32x16_bf16, acc f32x16[4][2].
// ---------------------------------------------------------------------------

typedef __attribute__((ext_vector_type(8))) short bf16x8;    // 8 bf16 = 4 VGPRs
typedef __attribute__((ext_vector_type(8))) unsigned short ushort8;
typedef __attribute__((ext_vector_type(16))) float f32x16;   // 32x32 MFMA acc

__device__ __forceinline__ unsigned short f2bf(float f) {
  unsigned int u = __float_as_uint(f);
  u += 0x7fffu + ((u >> 16) & 1u);
  return (unsigned short)(u >> 16);
}

// ---------------------------------------------------------------------------
// Fused prep kernel (unchanged from R4/R6).
// ---------------------------------------------------------------------------
__global__ __launch_bounds__(256) void prep_kernel(
    const float* __restrict__ x, unsigned short* __restrict__ xb,
    const float* __restrict__ w, unsigned short* __restrict__ wq,
    int castBlocks) {
  if ((int)blockIdx.x < castBlocks) {
    const size_t i = ((size_t)blockIdx.x * 256 + threadIdx.x) * 8;
    const float4 a = *(const float4*)(x + i);
    const float4 b = *(const float4*)(x + i + 4);
    ushort8 o = {f2bf(a.x), f2bf(a.y), f2bf(a.z), f2bf(a.w),
                 f2bf(b.x), f2bf(b.y), f2bf(b.z), f2bf(b.w)};
    *(ushort8*)(xb + i) = o;
    return;
  }
  const int qb   = blockIdx.x - castBlocks;
  const int lane = threadIdx.x & 63;
  const int wv   = threadIdx.x >> 6;
  const size_t base = (((size_t)qb * 4 + wv) * 256) + (size_t)lane * 4;
  const float4 v = *(const float4*)(w + base);

  float mn = fminf(fminf(v.x, v.y), fminf(v.z, v.w));
  float mx = fmaxf(fmaxf(v.x, v.y), fmaxf(v.z, v.w));
#pragma unroll
  for (int off = 1; off <= 4; off <<= 1) {
    mn = fminf(mn, __shfl_xor(mn, off));
    mx = fmaxf(mx, __shfl_xor(mx, off));
  }
  const float sub_min = fminf(mn, 0.0f);
  const float sub_max = fmaxf(mx, 0.0f);
  const float scale_raw = fmaxf(sub_max - sub_min, 1e-8f) / 15.0f;

  float smn = scale_raw, smx = scale_raw, supermin = sub_min;
#pragma unroll
  for (int off = 8; off <= 32; off <<= 1) {
    smn = fminf(smn, __shfl_xor(smn, off));
    smx = fmaxf(smx, __shfl_xor(smx, off));
    supermin = fminf(supermin, __shfl_xor(supermin, off));
  }
  const float s_range = fmaxf(smx - smn, 1e-8f);
  float s_int = rintf((scale_raw - smn) / s_range * 63.0f);
  s_int = fminf(fmaxf(s_int, 0.0f), 63.0f);
  float scale = s_int / 63.0f * s_range + smn;
  scale = fmaxf(scale, 1e-8f);
  const float inv_scale = 1.0f / scale;

  const float sm  = __half2float(__float2half(supermin));
  const float adj = sub_min - sm;

  float e[4] = {v.x, v.y, v.z, v.w};
  ushort4 o;
  unsigned short* op = (unsigned short*)&o;
#pragma unroll
  for (int k = 0; k < 4; ++k) {
    const float t = (e[k] - sm) - adj;
    float qv = rintf(t * inv_scale);
    qv = fminf(fmaxf(qv, 0.0f), 15.0f);
    op[k] = f2bf((qv * scale + adj) + sm);
  }
  *(ushort4*)(wq + base) = o;
}

// ---------------------------------------------------------------------------
// bf16 MFMA GEMM, C[m,n] = sum_k A[m,k]*B[n,k] + bias[n]
// Block tile 256x128, BK=64, 256 thr = 4 waves (2x2), wave tile 128x64.
// MFMA 32x32x16: per wave-step 4(i) x 2(j) x 4(t) = 32 MFMAs, acc f32x16[4][2].
// LDS 48 KiB (2 blocks/CU). Layout: byte(t,row,khalf) = t*ROWS*32 + row*32
// + (khalf ^ ((row>>2)&1))*16. Quarter-wave reads cover all 8 bank-quads
// 2-way (free). Staging: dest = j*4096 + tid*16 (linear, gload_lds rule);
// source k-chunk pre-swizzled: skoff = ((tid&1)^((tid>>3)&1))*8.
// ---------------------------------------------------------------------------
#define BM 256
#define BN 128
#define BK 64

__device__ __forceinline__ void async_cp16(void* lds, const void* g) {
  __builtin_amdgcn_global_load_lds(
      (__attribute__((address_space(1))) void*)(void*)g,
      (__attribute__((address_space(3))) void*)lds, 16, 0, 0);
}

__global__ __launch_bounds__(256, 2) void gemm_bt_kernel(
    const unsigned short* __restrict__ A,   // [M][K] bf16 bits
    const unsigned short* __restrict__ B,   // [N][K] bf16 bits (fq weight)
    const float* __restrict__ bias,         // [N]
    float* __restrict__ C,                  // [M][N] f32
    int M, int N, int K) {
  __shared__ unsigned short lds_a[BM * BK];   // 32 KiB: 4 groups x 8192 B
  __shared__ unsigned short lds_b[BN * BK];   // 16 KiB: 4 groups x 4096 B

  const int tid  = threadIdx.x;
  const int lane = tid & 63;
  const int wv   = tid >> 6;
  const int wm   = wv >> 1;          // wave row (128 rows each)
  const int wn   = wv & 1;           // wave col (64 cols each)
  const int bx   = blockIdx.x;       // N tile (128)
  const int by   = blockIdx.y;       // M tile (256)

  // --- staging: thread t -> row t>>1, slot t&1 (16 B each).
  // Slot s of row r must hold khalf = s ^ ((r>>2)&1); r = tid>>1 => r bit2 =
  // tid bit3. A issue j: k16-group j>>1, row-half j&1; dest = j*4096 + tid*16.
  const int srow  = tid >> 1;                               // 0..127
  const int skoff = (((tid & 1) ^ ((tid >> 3) & 1))) * 8;   // swizzled k8-half
  const unsigned short* gA0 = A + (size_t)(by * BM + srow) * K + skoff;
  const unsigned short* gA1 = gA0 + (size_t)128 * K;
  const unsigned short* gB0 = B + (size_t)(bx * BN + srow) * K + skoff;

  // --- fragment reads: row = base + (lane&31), khalf = lane>>5,
  // slot = khalf ^ ((row>>2)&1) = khalf ^ ((r32>>2)&1)  (base rows have bit2=0).
  const int r32   = lane & 31;
  const int kslot = (((lane >> 5) ^ ((r32 >> 2) & 1))) * 16;  // byte offset
  const int abase = (wm * 128 + r32) * 32 + kslot; // bytes within a k16-group
  const int bbase = (wn * 64  + r32) * 32 + kslot;

  f32x16 acc[4][2] = {};   // 128 f32 accumulators (AGPR)

  for (int k0 = 0; k0 < K; k0 += BK) {
#pragma unroll
    for (int j = 0; j < 8; ++j) {
      const unsigned short* src = (j & 1) ? gA1 : gA0;
      async_cp16((char*)lds_a + j * 4096 + tid * 16, src + k0 + (j >> 1) * 16);
    }
#pragma unroll
    for (int j = 0; j < 4; ++j)
      async_cp16((char*)lds_b + j * 4096 + tid * 16, gB0 + k0 + j * 16);
    __syncthreads();   // drain staging

#pragma unroll
    for (int h = 0; h < 2; ++h) {
      bf16x8 af[4][2], bfr[2][2];
#pragma unroll
      for (int t2 = 0; t2 < 2; ++t2) {
        const int t = 2 * h + t2;
#pragma unroll
        for (int i = 0; i < 4; ++i)
          af[i][t2] = *(const bf16x8*)((const char*)lds_a + t * 8192 + abase + i * 1024);
#pragma unroll
        for (int j = 0; j < 2; ++j)
          bfr[j][t2] = *(const bf16x8*)((const char*)lds_b + t * 4096 + bbase + j * 1024);
      }
#pragma unroll
      for (int i = 0; i < 4; ++i)
#pragma unroll
        for (int j = 0; j < 2; ++j)
#pragma unroll
          for (int t2 = 0; t2 < 2; ++t2)
            acc[i][j] = __builtin_amdgcn_mfma_f32_32x32x16_bf16(
                af[i][t2], bfr[j][t2], acc[i][j], 0, 0, 0);
    }
    __syncthreads();   // protect LDS before next stage
  }

  // Epilogue. 32x32 C/D layout: col = lane&31, row = (r&3) + 8*(r>>2) + 4*(lane>>5)
  const int rbase = by * BM + wm * 128 + 4 * (lane >> 5);
  const int cbase = bx * BN + wn * 64 + r32;
#pragma unroll
  for (int j = 0; j < 2; ++j) {
    const int c = cbase + j * 32;
    const float bv = bias[c];
#pragma unroll
    for (int i = 0; i < 4; ++i) {
#pragma unroll
      for (int r = 0; r < 16; ++r) {
        const int row = rbase + i * 32 + (r & 3) + 8 * (r >> 2);
        C[(size_t)row * N + c] = acc[i][j][r] + bv;
      }
    }
  }
}

// ---------------------------------------------------------------------------
extern "C" void kernel_launch(void* const* d_in, const int* in_sizes, int n_in,
                              void* d_out, int out_size, void* d_ws, size_t ws_size,
                              hipStream_t stream) {
  const float* x    = (const float*)d_in[0];
  const float* w    = (const float*)d_in[1];
  const float* bias = (const float*)d_in[2];
  float* out = (float*)d_out;

  const long long xn = in_sizes[0];   // M*K
  const long long wn = in_sizes[1];   // N*K
  const int N = in_sizes[2];
  const int K = (int)(wn / N);
  const int M = (int)(xn / K);

  unsigned short* xb = (unsigned short*)d_ws;
  unsigned short* wb = xb + (size_t)M * K;

  const int castBlocks  = (int)(xn / (256 * 8));    // 8 elems/thread
  const int quantBlocks = (int)(wn / (256 * 4));    // 1024 elems/block
  prep_kernel<<<castBlocks + quantBlocks, 256, 0, stream>>>(x, xb, w, wb,
                                                            castBlocks);
  gemm_bt_kernel<<<dim3(N / BN, M / BM), 256, 0, stream>>>(xb, wb, bias, out,
                                                           M, N, K);
}

// Round 7
// 283.504 us; speedup vs baseline: 1.1329x; 1.1329x over previous
//
#include <hip/hip_runtime.h>
#include <hip/hip_bf16.h>
#include <hip/hip_fp16.h>

// ---------------------------------------------------------------------------
// FakeQuantLinear (Q4_K_M fake-quant + GEMM): out = x @ fq(W)^T + bias
// R13: revert GEMM inner loop to R6 exactly (proven best: 131us, 1049 TF,
//      0 bank conflicts). 32x32 class closed: R10/R12 showed an identical
//      1.258e7-conflict penalty invariant under a provably-pattern-changing
//      swizzle -> 32B-row layouts carry a structural b128 penalty; R6's
//      128B-row slot-XOR layout measures 0. Schedule class closed (R7/R8/R9).
//      New in R13 (orthogonal, low-risk):
//      (1) T1 XCD-bijective swizzle on the GEMM grid (512 blocks, 512%8==0):
//          each XCD owns 2 contiguous by-rows -> A panels L2-resident.
//      (2) prep quant path widened to 8 elems/thread (sub=4 lanes,
//          super=32 lanes; min/max exact -> bit-identical results),
//          16B stores, quant blocks 16384->8192.
// ---------------------------------------------------------------------------

typedef __attribute__((ext_vector_type(8))) short bf16x8;    // 8 bf16 = 4 VGPRs
typedef __attribute__((ext_vector_type(8))) unsigned short ushort8;
typedef __attribute__((ext_vector_type(4))) float f32x4;     // MFMA acc

__device__ __forceinline__ unsigned short f2bf(float f) {
  unsigned int u = __float_as_uint(f);
  u += 0x7fffu + ((u >> 16) & 1u);
  return (unsigned short)(u >> 16);
}

// ---------------------------------------------------------------------------
// Fused prep kernel. Cast: 8 f32->bf16 per thread (unchanged).
// Quant: 8 elems/thread; sub-block (32 elems) = 4 lanes; super-group
// (256 elems) = 32 lanes; wave = 2 super-groups; block = 8 (2048 elems).
// ---------------------------------------------------------------------------
__global__ __launch_bounds__(256) void prep_kernel(
    const float* __restrict__ x, unsigned short* __restrict__ xb,
    const float* __restrict__ w, unsigned short* __restrict__ wq,
    int castBlocks) {
  if ((int)blockIdx.x < castBlocks) {
    const size_t i = ((size_t)blockIdx.x * 256 + threadIdx.x) * 8;
    const float4 a = *(const float4*)(x + i);
    const float4 b = *(const float4*)(x + i + 4);
    ushort8 o = {f2bf(a.x), f2bf(a.y), f2bf(a.z), f2bf(a.w),
                 f2bf(b.x), f2bf(b.y), f2bf(b.z), f2bf(b.w)};
    *(ushort8*)(xb + i) = o;
    return;
  }
  const int qb   = blockIdx.x - castBlocks;
  const int lane = threadIdx.x & 63;
  const int wv   = threadIdx.x >> 6;
  // wave covers 512 elems = 2 super-groups; lane>>5 selects the super-group,
  // lane&31 indexes 8-elem chunks within it.
  const size_t base = ((size_t)qb * 8 + wv * 2 + (lane >> 5)) * 256 +
                      (size_t)(lane & 31) * 8;
  const float4 v0 = *(const float4*)(w + base);
  const float4 v1 = *(const float4*)(w + base + 4);
  float e[8] = {v0.x, v0.y, v0.z, v0.w, v1.x, v1.y, v1.z, v1.w};

  float mn = e[0], mx = e[0];
#pragma unroll
  for (int k = 1; k < 8; ++k) {
    mn = fminf(mn, e[k]);
    mx = fmaxf(mx, e[k]);
  }
  // sub-block reduction over 4 lanes (32 elems)
#pragma unroll
  for (int off = 1; off <= 2; off <<= 1) {
    mn = fminf(mn, __shfl_xor(mn, off));
    mx = fmaxf(mx, __shfl_xor(mx, off));
  }
  const float sub_min = fminf(mn, 0.0f);
  const float sub_max = fmaxf(mx, 0.0f);
  const float scale_raw = fmaxf(sub_max - sub_min, 1e-8f) / 15.0f;

  // super-group reduction over the 8 sub-blocks (32 lanes)
  float smn = scale_raw, smx = scale_raw, supermin = sub_min;
#pragma unroll
  for (int off = 4; off <= 16; off <<= 1) {
    smn = fminf(smn, __shfl_xor(smn, off));
    smx = fmaxf(smx, __shfl_xor(smx, off));
    supermin = fminf(supermin, __shfl_xor(supermin, off));
  }
  const float s_range = fmaxf(smx - smn, 1e-8f);
  float s_int = rintf((scale_raw - smn) / s_range * 63.0f);
  s_int = fminf(fmaxf(s_int, 0.0f), 63.0f);
  float scale = s_int / 63.0f * s_range + smn;
  scale = fmaxf(scale, 1e-8f);
  const float inv_scale = 1.0f / scale;

  const float sm  = __half2float(__float2half(supermin));
  const float adj = sub_min - sm;

  ushort8 o;
#pragma unroll
  for (int k = 0; k < 8; ++k) {
    const float t = (e[k] - sm) - adj;
    float qv = rintf(t * inv_scale);
    qv = fminf(fmaxf(qv, 0.0f), 15.0f);
    o[k] = f2bf((qv * scale + adj) + sm);
  }
  *(ushort8*)(wq + base) = o;
}

// ---------------------------------------------------------------------------
// bf16 MFMA GEMM, C[m,n] = sum_k A[m,k]*B[n,k] + bias[n]  (R6 inner loop)
// Block tile 256x128, BK=64, single-buffered; 4 waves (2x2); wave tile
// 128x64 = 8x4 MFMA 16x16x32 per 32-k half (64 MFMA/wave/iter).
// LDS rows = 64 ushorts = 8x16B chunks; slot s of row r holds global chunk
// s^(r&7) -> readers spread over all 8 bank-groups 2-way (conflict-free).
// Grid: 1D, XCD-bijective swizzle (nwg % 8 == 0 for this shape).
// ---------------------------------------------------------------------------
#define BM 256
#define BN 128
#define BK 64

__device__ __forceinline__ void async_cp16(void* lds, const void* g) {
  __builtin_amdgcn_global_load_lds(
      (__attribute__((address_space(1))) void*)(void*)g,
      (__attribute__((address_space(3))) void*)lds, 16, 0, 0);
}

__global__ __launch_bounds__(256, 2) void gemm_bt_kernel(
    const unsigned short* __restrict__ A,   // [M][K] bf16 bits
    const unsigned short* __restrict__ B,   // [N][K] bf16 bits (fq weight)
    const float* __restrict__ bias,         // [N]
    float* __restrict__ C,                  // [M][N] f32
    int M, int N, int K) {
  __shared__ unsigned short lds_a[BM * BK];   // 32 KiB
  __shared__ unsigned short lds_b[BN * BK];   // 16 KiB

  const int tid  = threadIdx.x;
  const int lane = tid & 63;
  const int wv   = tid >> 6;
  const int wm   = wv >> 1;          // wave row (128 rows each)
  const int wn   = wv & 1;           // wave col (64 cols each)

  // XCD-bijective swizzle: consecutive physical ids round-robin across XCDs;
  // remap so XCD x owns logical chunk [x*cpx, (x+1)*cpx) (contiguous by-rows).
  const int nbx = N / BN;
  const int nwg = (int)gridDim.x;
  const int id  = (int)blockIdx.x;
  int swz = id;
  if ((nwg & 7) == 0) {
    const int cpx = nwg >> 3;
    swz = (id & 7) * cpx + (id >> 3);
  }
  const int bx = swz % nbx;          // N tile (128)
  const int by = swz / nbx;          // M tile (256)

  // staging: issue j covers rows j*32..j*32+31. Thread t -> row j*32+(t>>3),
  // slot t&7 (LDS offset = j*2048 + t*8 ushorts = uniform base + lane*16B).
  // Fetch global chunk (t&7)^((t>>3)&7) so slot s of row r holds s^(r&7).
  const int rloc = tid >> 3;                       // 0..31
  const int csw  = (tid & 7) ^ (rloc & 7);         // swizzled chunk
  const int koff = csw * 8;                        // ushort offset in row

  const unsigned short* gA[8];
  const unsigned short* gB[4];
#pragma unroll
  for (int j = 0; j < 8; ++j)
    gA[j] = A + (size_t)(by * BM + j * 32 + rloc) * K + koff;
#pragma unroll
  for (int j = 0; j < 4; ++j)
    gB[j] = B + (size_t)(bx * BN + j * 32 + rloc) * K + koff;

  f32x4 acc[8][4] = {};

  // fragment addressing: m/n = lane&15; k-chunk q = (lane>>4) + 4*half;
  // stored at slot q^(lane&7) (row&7 == lane&7 for all rows we touch).
  const int arow   = wm * 128 + (lane & 15);
  const int brow   = wn * 64 + (lane & 15);
  const int kslot0 = (((lane >> 4) ^ (lane & 7))) * 8;   // half 0
  const int kslot1 = kslot0 ^ 32;                        // half 1 (chunk+4)

  for (int k0 = 0; k0 < K; k0 += BK) {
#pragma unroll
    for (int j = 0; j < 8; ++j)
      async_cp16(lds_a + j * 2048 + tid * 8, gA[j] + k0);
#pragma unroll
    for (int j = 0; j < 4; ++j)
      async_cp16(lds_b + j * 2048 + tid * 8, gB[j] + k0);
    __syncthreads();   // drain staging

#pragma unroll
    for (int h = 0; h < 2; ++h) {
      const int ks = h ? kslot1 : kslot0;
      bf16x8 af[8], bfr[4];
#pragma unroll
      for (int i = 0; i < 8; ++i)
        af[i] = *(const bf16x8*)(lds_a + (arow + i * 16) * BK + ks);
#pragma unroll
      for (int j = 0; j < 4; ++j)
        bfr[j] = *(const bf16x8*)(lds_b + (brow + j * 16) * BK + ks);

#pragma unroll
      for (int i = 0; i < 8; ++i)
#pragma unroll
        for (int j = 0; j < 4; ++j)
          acc[i][j] = __builtin_amdgcn_mfma_f32_16x16x32_bf16(af[i], bfr[j],
                                                              acc[i][j], 0, 0, 0);
    }
    __syncthreads();   // protect LDS before next stage
  }

  // Epilogue. C/D layout: col = lane&15, row = (lane>>4)*4 + reg
  const int rbase = by * BM + wm * 128 + (lane >> 4) * 4;
  const int cbase = bx * BN + wn * 64 + (lane & 15);
#pragma unroll
  for (int j = 0; j < 4; ++j) {
    const int c = cbase + j * 16;
    const float bv = bias[c];
#pragma unroll
    for (int i = 0; i < 8; ++i) {
#pragma unroll
      for (int r = 0; r < 4; ++r) {
        C[(size_t)(rbase + i * 16 + r) * N + c] = acc[i][j][r] + bv;
      }
    }
  }
}

// ---------------------------------------------------------------------------
extern "C" void kernel_launch(void* const* d_in, const int* in_sizes, int n_in,
                              void* d_out, int out_size, void* d_ws, size_t ws_size,
                              hipStream_t stream) {
  const float* x    = (const float*)d_in[0];
  const float* w    = (const float*)d_in[1];
  const float* bias = (const float*)d_in[2];
  float* out = (float*)d_out;

  const long long xn = in_sizes[0];   // M*K
  const long long wn = in_sizes[1];   // N*K
  const int N = in_sizes[2];
  const int K = (int)(wn / N);
  const int M = (int)(xn / K);

  unsigned short* xb = (unsigned short*)d_ws;
  unsigned short* wb = xb + (size_t)M * K;

  const int castBlocks  = (int)(xn / (256 * 8));    // 8 elems/thread
  const int quantBlocks = (int)(wn / (256 * 8));    // 2048 elems/block
  prep_kernel<<<castBlocks + quantBlocks, 256, 0, stream>>>(x, xb, w, wb,
                                                            castBlocks);
  const int nwg = (N / BN) * (M / BM);
  gemm_bt_kernel<<<nwg, 256, 0, stream>>>(xb, wb, bias, out, M, N, K);
}